// Round 10
// baseline (164.621 us; speedup 1.0000x reference)
//
#include <hip/hip_runtime.h>
#include <stdint.h>

#define KN 32      // neighbors
#define NF 128     // feature dim
#define NH 4       // heads
#define HD 256     // H*D
#define NC 40      // classes
#define NPB 8      // nodes per block
#define NBUF 4     // LDS tile buffers (depth-3 async pipeline)

// ws layout (floats): [0,512)=w_src[h][f], [512,1024)=w_dst[h][f],
//   [1024,21504)=MT[cls][h*128+f], [21504,21504+4*n)=ei[n][h]
#define WS_WSRC 0
#define WS_WDST 512
#define WS_MT   1024
#define WS_EI   (1024 + NC * 512)

static __device__ __forceinline__ unsigned short bf16_of(float x) {
    union { float f; unsigned u; } v; v.f = x;
    unsigned r = v.u + 0x7FFFu + ((v.u >> 16) & 1u);
    return (unsigned short)(r >> 16);
}
static __device__ __forceinline__ float f_of_bf16(unsigned short b) {
    union { unsigned u; float f; } v; v.u = ((unsigned)b) << 16; return v.f;
}

// w_src[h][f] = sum_d W[f][h*64+d] * a_src[h][d]  (same for dst)
__global__ void gat_prep_ws(const float* __restrict__ W,
                            const float* __restrict__ a_src,
                            const float* __restrict__ a_dst,
                            float* __restrict__ ws)
{
    int g = blockIdx.x * blockDim.x + threadIdx.x;
    if (g >= 1024) return;
    int which = g >> 9, h = (g >> 7) & 3, f = g & 127;
    const float* a = which ? a_dst : a_src;
    float s = 0.f;
    #pragma unroll 8
    for (int d = 0; d < 64; ++d)
        s = fmaf(W[f * HD + h * 64 + d], a[h * 64 + d], s);
    ws[g] = s;
}

// MT[cls][h*128+f] = sum_d W[f][h*64+d] * cls_w[h*64+d][cls]
__global__ void gat_prep_mt(const float* __restrict__ W,
                            const float* __restrict__ cls_w,
                            float* __restrict__ ws)
{
    int g = blockIdx.x * blockDim.x + threadIdx.x;
    if (g >= NC * 512) return;
    int cls = g >> 9, c = g & 511;
    int h = c >> 7, f = c & 127;
    float s = 0.f;
    #pragma unroll 8
    for (int d = 0; d < 64; ++d)
        s = fmaf(W[f * HD + h * 64 + d], cls_w[(h * 64 + d) * NC + cls], s);
    ws[WS_MT + (size_t)cls * 512 + c] = s;
}

// ei[n][h] = sum_f nodef[n][f] * w_src[h][f]
__global__ void gat_prep_ei(const float* __restrict__ nodef,
                            float* __restrict__ ws, int n_nodes)
{
    const int t = threadIdx.x;
    const int lane = t & 63;
    const int node = blockIdx.x * 64 + (t >> 6) * 16 + (lane >> 2);
    const int q = lane & 3;
    if (node >= n_nodes) return;
    const float* wsrc = ws + WS_WSRC;
    const float4* xp = (const float4*)(nodef + (size_t)node * NF + q * 32);
    float p0 = 0.f, p1 = 0.f, p2 = 0.f, p3 = 0.f;
    #pragma unroll
    for (int j = 0; j < 8; ++j) {
        float4 x  = xp[j];
        float4 w0 = *(const float4*)&wsrc[0 * NF + q * 32 + 4 * j];
        float4 w1 = *(const float4*)&wsrc[1 * NF + q * 32 + 4 * j];
        float4 w2 = *(const float4*)&wsrc[2 * NF + q * 32 + 4 * j];
        float4 w3 = *(const float4*)&wsrc[3 * NF + q * 32 + 4 * j];
        p0 += x.x*w0.x + x.y*w0.y + x.z*w0.z + x.w*w0.w;
        p1 += x.x*w1.x + x.y*w1.y + x.z*w1.z + x.w*w1.w;
        p2 += x.x*w2.x + x.y*w2.y + x.z*w2.z + x.w*w2.w;
        p3 += x.x*w3.x + x.y*w3.y + x.z*w3.z + x.w*w3.w;
    }
    #pragma unroll
    for (int st = 1; st < 4; st <<= 1) {
        p0 += __shfl_xor(p0, st); p1 += __shfl_xor(p1, st);
        p2 += __shfl_xor(p2, st); p3 += __shfl_xor(p3, st);
    }
    if (q == 0)
        *(float4*)&ws[WS_EI + (size_t)node * 4] = make_float4(p0, p1, p2, p3);
}

// async global->LDS, 16B per lane, wave-uniform LDS base (HW adds lane*16)
static __device__ __forceinline__ void stage16(const float* g, float* l) {
    __builtin_amdgcn_global_load_lds(
        (const __attribute__((address_space(1))) void*)g,
        (__attribute__((address_space(3))) void*)l, 16, 0, 0);
}

// stage node tile (32x128 fp32, 16 KB) into buf: each wave DMAs its 4 KB
#define STAGE(NI, BI) do {                                                     \
    const float* g_ = neigh + (size_t)(node0 + (NI)) * (KN * NF)               \
                      + wv * 1024 + lane * 4;                                  \
    float* l_ = &Xs[BI][wv * 1024];                                            \
    stage16(g_,       l_);                                                     \
    stage16(g_ + 256, l_ + 256);                                               \
    stage16(g_ + 512, l_ + 512);                                               \
    stage16(g_ + 768, l_ + 768);                                               \
} while (0)

// One node body. VMSTR = literal counted vmcnt wait for THIS iteration:
// outstanding after wait = stages for the 2 nodes still in flight.
#define BODY(I, VMSTR) do {                                                    \
    const int buf_ = (I) & (NBUF - 1);                                         \
    asm volatile(VMSTR);                      /* node I's DMA landed (own) */  \
    __builtin_amdgcn_sched_barrier(0);                                         \
    __builtin_amdgcn_s_barrier();             /* all waves' DMA landed */      \
    __builtin_amdgcn_sched_barrier(0);                                         \
    if ((I) + 3 < NPB) STAGE((I) + 3, ((I) + 3) & (NBUF - 1));                 \
    /* e_j from LDS: thread (kq,fq) reads row kq cols fq*4+32j */              \
    {                                                                          \
        const float4* xrow_ = (const float4*)&Xs[buf_][kq * NF];               \
        float4 x0_ = xrow_[fq], x1_ = xrow_[fq + 8];                           \
        float4 x2_ = xrow_[fq + 16], x3_ = xrow_[fq + 24];                     \
        float s0_ = 0.f, s1_ = 0.f, s2_ = 0.f, s3_ = 0.f;                      \
        s0_ += x0_.x*wd[0][0].x + x0_.y*wd[0][0].y + x0_.z*wd[0][0].z + x0_.w*wd[0][0].w; \
        s1_ += x0_.x*wd[1][0].x + x0_.y*wd[1][0].y + x0_.z*wd[1][0].z + x0_.w*wd[1][0].w; \
        s2_ += x0_.x*wd[2][0].x + x0_.y*wd[2][0].y + x0_.z*wd[2][0].z + x0_.w*wd[2][0].w; \
        s3_ += x0_.x*wd[3][0].x + x0_.y*wd[3][0].y + x0_.z*wd[3][0].z + x0_.w*wd[3][0].w; \
        s0_ += x1_.x*wd[0][1].x + x1_.y*wd[0][1].y + x1_.z*wd[0][1].z + x1_.w*wd[0][1].w; \
        s1_ += x1_.x*wd[1][1].x + x1_.y*wd[1][1].y + x1_.z*wd[1][1].z + x1_.w*wd[1][1].w; \
        s2_ += x1_.x*wd[2][1].x + x1_.y*wd[2][1].y + x1_.z*wd[2][1].z + x1_.w*wd[2][1].w; \
        s3_ += x1_.x*wd[3][1].x + x1_.y*wd[3][1].y + x1_.z*wd[3][1].z + x1_.w*wd[3][1].w; \
        s0_ += x2_.x*wd[0][2].x + x2_.y*wd[0][2].y + x2_.z*wd[0][2].z + x2_.w*wd[0][2].w; \
        s1_ += x2_.x*wd[1][2].x + x2_.y*wd[1][2].y + x2_.z*wd[1][2].z + x2_.w*wd[1][2].w; \
        s2_ += x2_.x*wd[2][2].x + x2_.y*wd[2][2].y + x2_.z*wd[2][2].z + x2_.w*wd[2][2].w; \
        s3_ += x2_.x*wd[3][2].x + x2_.y*wd[3][2].y + x2_.z*wd[3][2].z + x2_.w*wd[3][2].w; \
        s0_ += x3_.x*wd[0][3].x + x3_.y*wd[0][3].y + x3_.z*wd[0][3].z + x3_.w*wd[0][3].w; \
        s1_ += x3_.x*wd[1][3].x + x3_.y*wd[1][3].y + x3_.z*wd[1][3].z + x3_.w*wd[1][3].w; \
        s2_ += x3_.x*wd[2][3].x + x3_.y*wd[2][3].y + x3_.z*wd[2][3].z + x3_.w*wd[2][3].w; \
        s3_ += x3_.x*wd[3][3].x + x3_.y*wd[3][3].y + x3_.z*wd[3][3].z + x3_.w*wd[3][3].w; \
        _Pragma("unroll")                                                      \
        for (int st = 1; st < 8; st <<= 1) {                                   \
            s0_ += __shfl_xor(s0_, st); s1_ += __shfl_xor(s1_, st);            \
            s2_ += __shfl_xor(s2_, st); s3_ += __shfl_xor(s3_, st);            \
        }                                                                      \
        if (fq == 0) {                                                         \
            e_lds[kq] = s0_; e_lds[32 + kq] = s1_;                             \
            e_lds[64 + kq] = s2_; e_lds[96 + kq] = s3_;                        \
        }                                                                      \
    }                                                                          \
    asm volatile("s_waitcnt lgkmcnt(0)");     /* own e-writes retired */       \
    __builtin_amdgcn_sched_barrier(0);                                         \
    __builtin_amdgcn_s_barrier();             /* e visible to all */           \
    __builtin_amdgcn_sched_barrier(0);                                         \
    /* fused softmax + aggregation: head=wv, cols (lane, lane+64) */           \
    {                                                                          \
        const float ei_ = eiv[(I)];                                            \
        float ss_ = 0.f, zx_ = 0.f, zy_ = 0.f;                                 \
        _Pragma("unroll")                                                      \
        for (int m = 0; m < 8; ++m) {                                          \
            float4 ev_ = *(const float4*)&e_lds[wv * KN + m * 4];              \
            float el_[4] = {ev_.x, ev_.y, ev_.z, ev_.w};                       \
            _Pragma("unroll")                                                  \
            for (int kk = 0; kk < 4; ++kk) {                                   \
                float z_ = ei_ + el_[kk];                                      \
                float l2_ = fmaxf(z_, 0.2f * z_);                              \
                float p_ = __expf(l2_);                                        \
                ss_ += p_;                                                     \
                float xa_ = Xs[buf_][(m * 4 + kk) * NF + lane];                \
                float xb_ = Xs[buf_][(m * 4 + kk) * NF + 64 + lane];           \
                zx_ = fmaf(p_, xa_, zx_);                                      \
                zy_ = fmaf(p_, xb_, zy_);                                      \
            }                                                                  \
        }                                                                      \
        float inv_ = 1.f / ss_;                                                \
        zlB[(I)][wv * 128 + lane]      = bf16_of(zx_ * inv_);                  \
        zlB[(I)][wv * 128 + 64 + lane] = bf16_of(zy_ * inv_);                  \
    }                                                                          \
} while (0)

__global__ __launch_bounds__(256, 2)
void gat_main(const float* __restrict__ neigh,
              const float* __restrict__ ws,
              float* __restrict__ out, int n_nodes)
{
    __shared__ __align__(16) float Xs[NBUF][KN * NF];        // 64 KB, linear (DMA dest)
    __shared__ __align__(16) unsigned short zlB[NPB][512];   // 8 KB bf16
    __shared__ __align__(16) float e_lds[NH * KN];           // 512 B

    const int t    = threadIdx.x;
    const int lane = t & 63;
    const int wv   = t >> 6;        // wave id == head in agg phase
    const int kq   = t >> 3;        // neighbor row (e_j phase)
    const int fq   = t & 7;         // feature-slice (e_j phase)
    const float* wdst = ws + WS_WDST;
    const float* MT   = ws + WS_MT;
    const float* ei_g = ws + WS_EI;

    const int node0 = blockIdx.x * NPB;
    if (node0 >= n_nodes) return;

    // register caches loaded BEFORE the DMA stages: vmcnt is FIFO-ordered, so
    // body-0's vmcnt(8) also retires these (no compiler-forced drain later).
    float4 wd[4][4];
    #pragma unroll
    for (int h = 0; h < 4; ++h)
        #pragma unroll
        for (int j = 0; j < 4; ++j)
            wd[h][j] = *(const float4*)&wdst[h * NF + fq * 4 + 32 * j];
    float eiv[NPB];
    #pragma unroll
    for (int i = 0; i < NPB; ++i)
        eiv[i] = ei_g[(size_t)(node0 + i) * 4 + wv];

    // prologue: DMA nodes 0,1,2 into bufs 0,1,2 (12 issues/wave in flight)
    STAGE(0, 0);
    STAGE(1, 1);
    STAGE(2, 2);

    BODY(0, "s_waitcnt vmcnt(8)");
    BODY(1, "s_waitcnt vmcnt(8)");
    BODY(2, "s_waitcnt vmcnt(8)");
    BODY(3, "s_waitcnt vmcnt(8)");
    BODY(4, "s_waitcnt vmcnt(8)");
    BODY(5, "s_waitcnt vmcnt(8)");
    BODY(6, "s_waitcnt vmcnt(4)");
    BODY(7, "s_waitcnt vmcnt(0)");

    __syncthreads();   // zl visible; nothing left in flight

    // ---- fused classifier: y[i][cls] = zl[i][:] . MT[cls][:] ----
    float* ypart = (float*)&Xs[0][0];   // Xs dead; ypart[s][i][cls]
    {
        int cls = t & 63, s = t >> 6;
        if (cls < NC) {
            const float4* mp = (const float4*)&MT[(size_t)cls * 512 + s * 128];
            float acc[NPB];
            #pragma unroll
            for (int i = 0; i < NPB; ++i) acc[i] = 0.f;
            #pragma unroll 2
            for (int c4 = 0; c4 < 32; ++c4) {
                float4 mv = mp[c4];
                #pragma unroll
                for (int i = 0; i < NPB; ++i) {
                    ushort4 zv = *(const ushort4*)&zlB[i][s * 128 + c4 * 4];
                    acc[i] += f_of_bf16(zv.x) * mv.x + f_of_bf16(zv.y) * mv.y
                            + f_of_bf16(zv.z) * mv.z + f_of_bf16(zv.w) * mv.w;
                }
            }
            #pragma unroll
            for (int i = 0; i < NPB; ++i)
                ypart[s * (NPB * NC) + i * NC + cls] = acc[i];
        }
    }
    __syncthreads();
    #pragma unroll
    for (int rep = 0; rep < 2; ++rep) {
        int p = t + rep * 256;
        if (p < NPB * NC) {
            float y = ypart[p] + ypart[NPB * NC + p]
                    + ypart[2 * NPB * NC + p] + ypart[3 * NPB * NC + p];
            out[(size_t)node0 * NC + p] = y;
        }
    }
}

extern "C" void kernel_launch(void* const* d_in, const int* in_sizes, int n_in,
                              void* d_out, int out_size, void* d_ws, size_t ws_size,
                              hipStream_t stream) {
    const float* nodef = (const float*)d_in[0];
    const float* neigh = (const float*)d_in[1];
    const float* W     = (const float*)d_in[2];
    const float* a_src = (const float*)d_in[3];
    const float* a_dst = (const float*)d_in[4];
    const float* cls_w = (const float*)d_in[5];
    float* out = (float*)d_out;
    float* ws  = (float*)d_ws;

    const int n_nodes = in_sizes[0] / NF;   // 20000

    hipLaunchKernelGGL(gat_prep_ws, dim3(4), dim3(256), 0, stream, W, a_src, a_dst, ws);
    hipLaunchKernelGGL(gat_prep_ei, dim3((n_nodes + 63) / 64), dim3(256), 0, stream,
                       nodef, ws, n_nodes);
    hipLaunchKernelGGL(gat_prep_mt, dim3((NC * 512 + 255) / 256), dim3(256), 0, stream,
                       W, cls_w, ws);
    hipLaunchKernelGGL(gat_main, dim3((n_nodes + NPB - 1) / NPB), dim3(256), 0, stream,
                       neigh, ws, out, n_nodes);
}

// Round 11
// 125.628 us; speedup vs baseline: 1.3104x; 1.3104x over previous
//
#include <hip/hip_runtime.h>

#define KN 32      // neighbors
#define NF 128     // feature dim
#define NH 4       // heads
#define HD 256     // H*D
#define NC 40      // classes
#define NPB 8      // nodes per block
#define XSS 132    // Xs row stride (floats): stage 2-way, agg reads bank-unique

// ws layout (floats): [0,512)=w_src[h][f], [512,1024)=w_dst[h][f],
//   [1024,21504)=MT[cls][h*128+f], [21504,21504+4*n)=ei[n][h]
#define WS_WSRC 0
#define WS_WDST 512
#define WS_MT   1024
#define WS_EI   (1024 + NC * 512)

// merged prep: blocks 0-3 -> w_src/w_dst; blocks 4-83 -> MT
__global__ void gat_prep_wm(const float* __restrict__ W,
                            const float* __restrict__ a_src,
                            const float* __restrict__ a_dst,
                            const float* __restrict__ cls_w,
                            float* __restrict__ ws)
{
    if (blockIdx.x < 4) {
        int g = blockIdx.x * 256 + threadIdx.x;
        int which = g >> 9, h = (g >> 7) & 3, f = g & 127;
        const float* a = which ? a_dst : a_src;
        float s = 0.f;
        #pragma unroll 8
        for (int d = 0; d < 64; ++d)
            s = fmaf(W[f * HD + h * 64 + d], a[h * 64 + d], s);
        ws[g] = s;
    } else {
        int g = (blockIdx.x - 4) * 256 + threadIdx.x;
        if (g >= NC * 512) return;
        int cls = g >> 9, c = g & 511;
        int h = c >> 7, f = c & 127;
        float s = 0.f;
        #pragma unroll 8
        for (int d = 0; d < 64; ++d)
            s = fmaf(W[f * HD + h * 64 + d], cls_w[(h * 64 + d) * NC + cls], s);
        ws[WS_MT + (size_t)cls * 512 + c] = s;
    }
}

// ei[n][h] = sum_f nodef[n][f] * w_src[h][f]
__global__ void gat_prep_ei(const float* __restrict__ nodef,
                            float* __restrict__ ws, int n_nodes)
{
    const int t = threadIdx.x;
    const int lane = t & 63;
    const int node = blockIdx.x * 64 + (t >> 6) * 16 + (lane >> 2);
    const int q = lane & 3;
    if (node >= n_nodes) return;
    const float* wsrc = ws + WS_WSRC;
    const float4* xp = (const float4*)(nodef + (size_t)node * NF + q * 32);
    float p0 = 0.f, p1 = 0.f, p2 = 0.f, p3 = 0.f;
    #pragma unroll
    for (int j = 0; j < 8; ++j) {
        float4 x  = xp[j];
        float4 w0 = *(const float4*)&wsrc[0 * NF + q * 32 + 4 * j];
        float4 w1 = *(const float4*)&wsrc[1 * NF + q * 32 + 4 * j];
        float4 w2 = *(const float4*)&wsrc[2 * NF + q * 32 + 4 * j];
        float4 w3 = *(const float4*)&wsrc[3 * NF + q * 32 + 4 * j];
        p0 += x.x*w0.x + x.y*w0.y + x.z*w0.z + x.w*w0.w;
        p1 += x.x*w1.x + x.y*w1.y + x.z*w1.z + x.w*w1.w;
        p2 += x.x*w2.x + x.y*w2.y + x.z*w2.z + x.w*w2.w;
        p3 += x.x*w3.x + x.y*w3.y + x.z*w3.z + x.w*w3.w;
    }
    #pragma unroll
    for (int st = 1; st < 4; st <<= 1) {
        p0 += __shfl_xor(p0, st); p1 += __shfl_xor(p1, st);
        p2 += __shfl_xor(p2, st); p3 += __shfl_xor(p3, st);
    }
    if (q == 0)
        *(float4*)&ws[WS_EI + (size_t)node * 4] = make_float4(p0, p1, p2, p3);
}

// LDS-only barrier: waits DS ops, does NOT drain vmcnt -> prefetch loads
// stay in flight across it (the __syncthreads drain was the R7 stall).
static __device__ __forceinline__ void lds_barrier() {
    __builtin_amdgcn_sched_barrier(0);
    asm volatile("s_waitcnt lgkmcnt(0)");
    __builtin_amdgcn_sched_barrier(0);
    __builtin_amdgcn_s_barrier();
    __builtin_amdgcn_sched_barrier(0);
}

// One node: stage tile, e_j dots from prefetch regs, ONE non-draining
// barrier, fused exp-softmax + aggregation (|e|max ~ 10 << fp32 exp range).
__device__ __forceinline__ void gat_body(
    int i_, float* __restrict__ XsB, float* __restrict__ eB,
    float* __restrict__ zrow, float4 xv[4], const float4 wd[4][4],
    const float eiv[NPB], const float* __restrict__ neigh,
    int node0, int kq, int fq, int wv, int lane)
{
    // stage tile into this parity's LDS buffer (fp32)
    #pragma unroll
    for (int j = 0; j < 4; ++j)
        *(float4*)&XsB[kq * XSS + fq * 4 + 32 * j] = xv[j];

    // e_j partial dots from fp32 registers
    float s0 = 0.f, s1 = 0.f, s2 = 0.f, s3 = 0.f;
    #pragma unroll
    for (int j = 0; j < 4; ++j) {
        float4 x = xv[j];
        s0 += x.x*wd[0][j].x + x.y*wd[0][j].y + x.z*wd[0][j].z + x.w*wd[0][j].w;
        s1 += x.x*wd[1][j].x + x.y*wd[1][j].y + x.z*wd[1][j].z + x.w*wd[1][j].w;
        s2 += x.x*wd[2][j].x + x.y*wd[2][j].y + x.z*wd[2][j].z + x.w*wd[2][j].w;
        s3 += x.x*wd[3][j].x + x.y*wd[3][j].y + x.z*wd[3][j].z + x.w*wd[3][j].w;
    }

    // depth-2 prefetch: xv dead, reload with node i_+2 (stays in flight
    // across the lds_barrier below - compiler emits counted vmcnt at use)
    if (i_ + 2 < NPB) {
        const float4* src = (const float4*)(neigh + ((size_t)(node0 + i_ + 2) * KN + kq) * NF);
        #pragma unroll
        for (int j = 0; j < 4; ++j) xv[j] = src[fq + 8 * j];
    }

    // reduce e_j over the 8 feature-slices
    #pragma unroll
    for (int st = 1; st < 8; st <<= 1) {
        s0 += __shfl_xor(s0, st); s1 += __shfl_xor(s1, st);
        s2 += __shfl_xor(s2, st); s3 += __shfl_xor(s3, st);
    }
    if (fq == 0) {                       // 32 writers -> 32 distinct banks
        eB[0 * KN + kq] = s0; eB[1 * KN + kq] = s1;
        eB[2 * KN + kq] = s2; eB[3 * KN + kq] = s3;
    }

    lds_barrier();     // e + tile visible; prefetch NOT drained

    // fused softmax + aggregation; thread owns (head=wv, cols lane,lane+64)
    // Xs read bank = (4*row + lane) % 32: unique per lane -> conflict-free.
    const float ei_h = eiv[i_];
    float ss = 0.f, zx = 0.f, zy = 0.f;
    #pragma unroll
    for (int m = 0; m < 8; ++m) {
        float4 evm = *(const float4*)&eB[wv * KN + m * 4];   // broadcast
        float el[4] = {evm.x, evm.y, evm.z, evm.w};
        #pragma unroll
        for (int kk = 0; kk < 4; ++kk) {
            float z_ = ei_h + el[kk];
            float l_ = fmaxf(z_, 0.2f * z_);       // LeakyReLU
            float p_ = __expf(l_);
            ss += p_;
            float xa = XsB[(m * 4 + kk) * XSS + lane];
            float xb = XsB[(m * 4 + kk) * XSS + 64 + lane];
            zx = fmaf(p_, xa, zx);
            zy = fmaf(p_, xb, zy);
        }
    }
    float inv = 1.f / ss;
    zrow[wv * NF + lane]      = zx * inv;
    zrow[wv * NF + 64 + lane] = zy * inv;
}

__global__ __launch_bounds__(256, 3)
void gat_main(const float* __restrict__ neigh,
              const float* __restrict__ ws,
              float* __restrict__ out, int n_nodes)
{
    __shared__ __align__(16) float Xs[2][KN * XSS];   // 33.8 KB dbuf tile
    __shared__ __align__(16) float zl[NPB][512];      // 16 KB aggregated feats
    __shared__ __align__(16) float e_lds[2][NH * KN]; // 1 KB dbuf logits

    const int t    = threadIdx.x;
    const int lane = t & 63;
    const int kq   = t >> 3;        // neighbor row 0..31
    const int fq   = t & 7;         // feature-slice id
    const int wv   = t >> 6;        // wave id == head in agg phase
    const float* wdst = ws + WS_WDST;
    const float* MT   = ws + WS_MT;
    const float* ei_g = ws + WS_EI;

    const int node0 = blockIdx.x * NPB;
    if (node0 >= n_nodes) return;

    // register caches (compiler may rematerialize wd from L1 - fine)
    float4 wd[4][4];
    #pragma unroll
    for (int h = 0; h < 4; ++h)
        #pragma unroll
        for (int j = 0; j < 4; ++j)
            wd[h][j] = *(const float4*)&wdst[h * NF + fq * 4 + 32 * j];
    float eiv[NPB];
    #pragma unroll
    for (int i = 0; i < NPB; ++i)
        eiv[i] = ei_g[(size_t)(node0 + i) * 4 + wv];

    // prologue: depth-2 prefetch (nodes node0, node0+1)
    float4 xvA[4], xvB[4];
    {
        const float4* sA = (const float4*)(neigh + ((size_t)node0 * KN + kq) * NF);
        const float4* sB = (const float4*)(neigh + ((size_t)(node0 + 1) * KN + kq) * NF);
        #pragma unroll
        for (int j = 0; j < 4; ++j) { xvA[j] = sA[fq + 8 * j]; xvB[j] = sB[fq + 8 * j]; }
    }

    #pragma unroll
    for (int ii = 0; ii < NPB; ii += 2) {
        gat_body(ii,     Xs[0], e_lds[0], zl[ii],     xvA, wd, eiv, neigh,
                 node0, kq, fq, wv, lane);
        gat_body(ii + 1, Xs[1], e_lds[1], zl[ii + 1], xvB, wd, eiv, neigh,
                 node0, kq, fq, wv, lane);
    }
    __syncthreads();   // full drain once per block - zl visible

    // ---- fused classifier: y[i][cls] = zl[i][:] . MT[cls][:] ----
    float* ypart = &Xs[0][0];   // Xs dead; ypart[s][i][cls]
    {
        int cls = t & 63, s = t >> 6;
        if (cls < NC) {
            const float4* mp = (const float4*)&MT[(size_t)cls * 512 + s * 128];
            float acc[NPB];
            #pragma unroll
            for (int i = 0; i < NPB; ++i) acc[i] = 0.f;
            #pragma unroll 2
            for (int c4 = 0; c4 < 32; ++c4) {
                float4 mv = mp[c4];
                #pragma unroll
                for (int i = 0; i < NPB; ++i) {
                    float4 zv = *(const float4*)&zl[i][s * 128 + c4 * 4];  // broadcast
                    acc[i] += zv.x * mv.x + zv.y * mv.y + zv.z * mv.z + zv.w * mv.w;
                }
            }
            #pragma unroll
            for (int i = 0; i < NPB; ++i)
                ypart[s * (NPB * NC) + i * NC + cls] = acc[i];
        }
    }
    __syncthreads();
    #pragma unroll
    for (int rep = 0; rep < 2; ++rep) {
        int p = t + rep * 256;
        if (p < NPB * NC) {
            float y = ypart[p] + ypart[NPB * NC + p]
                    + ypart[2 * NPB * NC + p] + ypart[3 * NPB * NC + p];
            out[(size_t)node0 * NC + p] = y;   // consecutive -> coalesced
        }
    }
}

extern "C" void kernel_launch(void* const* d_in, const int* in_sizes, int n_in,
                              void* d_out, int out_size, void* d_ws, size_t ws_size,
                              hipStream_t stream) {
    const float* nodef = (const float*)d_in[0];
    const float* neigh = (const float*)d_in[1];
    const float* W     = (const float*)d_in[2];
    const float* a_src = (const float*)d_in[3];
    const float* a_dst = (const float*)d_in[4];
    const float* cls_w = (const float*)d_in[5];
    float* out = (float*)d_out;
    float* ws  = (float*)d_ws;

    const int n_nodes = in_sizes[0] / NF;   // 20000

    hipLaunchKernelGGL(gat_prep_wm, dim3(4 + (NC * 512 + 255) / 256), dim3(256), 0, stream,
                       W, a_src, a_dst, cls_w, ws);
    hipLaunchKernelGGL(gat_prep_ei, dim3((n_nodes + 63) / 64), dim3(256), 0, stream,
                       nodef, ws, n_nodes);
    hipLaunchKernelGGL(gat_main, dim3((n_nodes + NPB - 1) / NPB), dim3(256), 0, stream,
                       neigh, ws, out, n_nodes);
}